// Round 3
// baseline (298.789 us; speedup 1.0000x reference)
//
#include <hip/hip_runtime.h>
#include <math.h>

#define BB 8
#define CH 128
#define HH 152
#define WWID 272
#define HWSZ (HH*WWID)
#define NDET 128
#define NHEAD 8
#define HDIM 16
#define DFF 512
#define NDB (BB*NDET)       // 1024 det blocks
#define NMIX (3*NDB)        // 3072 blocks: bid%3==1 -> det, else copy

__device__ __forceinline__ float dot4(float4 w, float4 u, float s) {
    s = fmaf(w.x, u.x, s);
    s = fmaf(w.y, u.y, s);
    s = fmaf(w.z, u.z, s);
    s = fmaf(w.w, u.w, s);
    return s;
}

// LayerNorm over 128 values held one-per-thread (t<128); ALL 256 threads must call.
__device__ __forceinline__ float block_layernorm(float v, int t,
        const float* __restrict__ gamma, const float* __restrict__ beta,
        float* redA, float* redB) {
    float s1 = v, s2 = v * v;
    #pragma unroll
    for (int off = 32; off >= 1; off >>= 1) {
        s1 += __shfl_xor(s1, off);
        s2 += __shfl_xor(s2, off);
    }
    if ((t & 63) == 0) { redA[t >> 6] = s1; redB[t >> 6] = s2; }
    __syncthreads();
    float sum = redA[0] + redA[1] + redA[2] + redA[3];
    float sq  = redB[0] + redB[1] + redB[2] + redB[3];
    __syncthreads();
    float m   = sum * (1.0f / 128.0f);
    float var = sq  * (1.0f / 128.0f) - m * m;
    float r = 0.f;
    if (t < CH) r = (v - m) * rsqrtf(var + 1e-5f) * gamma[t] + beta[t];
    return r;
}

__global__ __launch_bounds__(256) void er_fused(
    const float* __restrict__ x, const float* __restrict__ vis,
    const int* __restrict__ dets, const int* __restrict__ inds,
    const float* __restrict__ Wqkv, const float* __restrict__ bqkv,
    const float* __restrict__ Wo,   const float* __restrict__ bo,
    const float* __restrict__ W1,   const float* __restrict__ b1,
    const float* __restrict__ W2,   const float* __restrict__ b2,
    const float* __restrict__ g2,   const float* __restrict__ be2,
    const float* __restrict__ g3,   const float* __restrict__ be3,
    float* __restrict__ out, float* __restrict__ rows)
{
    const int bid = blockIdx.x;
    const int t   = threadIdx.x;

    int det_idx;
    if (rows) {
        // mixed grid: bid%3==1 is a det block; others stream-copy.
        // mod 3 is coprime to every power-of-2 dispatch stride, so each CU's
        // resident set is ~1/3 det + 2/3 copy -> copy BW hides det latency.
        const int r = bid % 3;
        if (r != 1) {
            const int cid = (bid / 3) * 2 + (r >> 1);   // 0..2047 unique
            const size_t n4 = (size_t)BB * CH * HWSZ / 4;
            const float4* s4 = (const float4*)x;
            float4* o4 = (float4*)out;
            size_t i = (size_t)cid * 256 + t;
            const size_t stride = (size_t)2048 * 256;
            for (; i < n4; i += stride) o4[i] = s4[i];
            return;
        }
        det_idx = bid / 3;
    } else {
        det_idx = bid;   // fallback path: det-only grid
    }

    __shared__ float kbuf[9][CH];
    __shared__ float qv[CH];
    __shared__ float qp[CH];
    __shared__ float kp[9][CH];
    __shared__ float vp[9][CH];
    __shared__ float att[NHEAD][9];
    __shared__ float aov[CH];
    __shared__ float tv[CH];
    __shared__ float h1[DFF];
    __shared__ float part[256];
    __shared__ float redA[4], redB[4];

    const int b = det_idx >> 7;
    const int n = det_idx & (NDET - 1);

    const int4 dv = *((const int4*)(dets + (size_t)(b * NDET + n) * 4));
    const int sx = dv.x, sy = dv.y, ex = dv.z, ey = dv.w;
    const int Lx = ex - sx, Ly = ey - sy;
    // cell edges (note: cells OVERLAP due to floor/ceil in reference)
    const int xs1 = sx + Lx / 3,        xs2 = sx + 2 * Lx / 3;
    const int xe0 = sx + (Lx + 2) / 3,  xe1 = sx + (2 * Lx + 2) / 3;
    const int ys1 = sy + Ly / 3,        ys2 = sy + 2 * Ly / 3;
    const int ye0 = sy + (Ly + 2) / 3,  ye1 = sy + (2 * Ly + 2) / 3;

    const int p = inds[b * NDET + n];

    // ---- q gather + vis positional embedding (threads 0..127) ----
    if (t < CH) {
        float qval = x[((size_t)b * CH + t) * HWSZ + p];
        float vv   = vis[(size_t)b * HWSZ + p];
        int vidx   = (int)(vv * 10.0f);
        float fr   = powf(10000.0f, -(float)(t & 126) * (1.0f / 128.0f));
        float ang  = 0.1f * (float)vidx * fr;
        float pe   = (t & 1) ? cosf(ang) : sinf(ang);
        qv[t] = qval + pe;
    }

    // ---- adaptive 3x3 pooling ----
    // 16 groups of 16 lanes; each group covers 64 x-positions with ONE float4
    // load per (channel,row). Box width <= 40 (+3 align slack) so one load
    // instruction covers the whole row. x-cell masks hoisted (depend on xx only).
    {
        const int g   = t >> 4;
        const int lx  = t & 15;
        const int sx4 = sx & ~3;              // 16B-aligned start
        const int xb  = sx4 + lx * 4;         // lane's base x
        const bool active = (xb < ex);        // lane touches the box at all

        float4 mx0, mx1, mx2;
        {
            float m0[4], m1[4], m2[4];
            #pragma unroll
            for (int e = 0; e < 4; ++e) {
                int xx = xb + e;
                m0[e] = (xx >= sx  && xx < xe0) ? 1.f : 0.f;
                m1[e] = (xx >= xs1 && xx < xe1) ? 1.f : 0.f;
                m2[e] = (xx >= xs2 && xx < ex ) ? 1.f : 0.f;
            }
            mx0 = make_float4(m0[0], m0[1], m0[2], m0[3]);
            mx1 = make_float4(m1[0], m1[1], m1[2], m1[3]);
            mx2 = make_float4(m2[0], m2[1], m2[2], m2[3]);
        }

        for (int c = 0; c < 8; ++c) {
            const int dd = g + c * 16;
            const float* base = x + ((size_t)b * CH + dd) * HWSZ + xb;
            float a[9] = {0.f,0.f,0.f,0.f,0.f,0.f,0.f,0.f,0.f};
            #pragma unroll 4
            for (int y = sy; y < ey; ++y) {
                float4 v = make_float4(0.f, 0.f, 0.f, 0.f);
                if (active) v = *(const float4*)(base + (size_t)y * WWID);
                float xc0 = dot4(mx0, v, 0.f);
                float xc1 = dot4(mx1, v, 0.f);
                float xc2 = dot4(mx2, v, 0.f);
                float my0 = (y < ye0) ? 1.f : 0.f;
                float my1 = (y >= ys1 && y < ye1) ? 1.f : 0.f;
                float my2 = (y >= ys2) ? 1.f : 0.f;
                a[0] = fmaf(my0, xc0, a[0]); a[1] = fmaf(my0, xc1, a[1]); a[2] = fmaf(my0, xc2, a[2]);
                a[3] = fmaf(my1, xc0, a[3]); a[4] = fmaf(my1, xc1, a[4]); a[5] = fmaf(my1, xc2, a[5]);
                a[6] = fmaf(my2, xc0, a[6]); a[7] = fmaf(my2, xc1, a[7]); a[8] = fmaf(my2, xc2, a[8]);
            }
            #pragma unroll
            for (int jj = 0; jj < 9; ++jj) {
                a[jj] += __shfl_xor(a[jj], 8);
                a[jj] += __shfl_xor(a[jj], 4);
                a[jj] += __shfl_xor(a[jj], 2);
                a[jj] += __shfl_xor(a[jj], 1);
            }
            if (lx == 0) {
                int w0 = xe0 - sx, w1 = xe1 - xs1, w2 = ex - xs2;
                int h0 = ye0 - sy, h1r = ye1 - ys1, h2 = ey - ys2;
                kbuf[0][dd] = a[0] / (float)(h0 * w0);
                kbuf[1][dd] = a[1] / (float)(h0 * w1);
                kbuf[2][dd] = a[2] / (float)(h0 * w2);
                kbuf[3][dd] = a[3] / (float)(h1r * w0);
                kbuf[4][dd] = a[4] / (float)(h1r * w1);
                kbuf[5][dd] = a[5] / (float)(h1r * w2);
                kbuf[6][dd] = a[6] / (float)(h2 * w0);
                kbuf[7][dd] = a[7] / (float)(h2 * w1);
                kbuf[8][dd] = a[8] / (float)(h2 * w2);
            }
        }
    }
    __syncthreads();

    // ---- qp = Wq @ q + bq ----
    if (t < CH) {
        const float4* wr = (const float4*)(Wqkv + (size_t)t * CH);
        const float4* qq = (const float4*)qv;
        float s = 0.f;
        #pragma unroll 8
        for (int i = 0; i < CH / 4; ++i) s = dot4(wr[i], qq[i], s);
        qp[t] = s + bqkv[t];
    }

    // ---- kp/vp = {Wk,Wv} @ k + {bk,bv} : 256 threads = 128 outs x {k,v} ----
    {
        const int o = t & (CH - 1);
        const int which = t >> 7;  // 0 -> k, 1 -> v
        const float4* wr = (const float4*)(Wqkv + (size_t)(CH + which * CH + o) * CH);
        float acc[9] = {0.f,0.f,0.f,0.f,0.f,0.f,0.f,0.f,0.f};
        #pragma unroll 4
        for (int i = 0; i < CH / 4; ++i) {
            float4 w = wr[i];
            #pragma unroll
            for (int s = 0; s < 9; ++s) {
                float4 kk = ((const float4*)(&kbuf[s][0]))[i];
                acc[s] = dot4(w, kk, acc[s]);
            }
        }
        float bias = bqkv[CH + which * CH + o];
        if (which == 0) {
            #pragma unroll
            for (int s = 0; s < 9; ++s) kp[s][o] = acc[s] + bias;
        } else {
            #pragma unroll
            for (int s = 0; s < 9; ++s) vp[s][o] = acc[s] + bias;
        }
    }
    __syncthreads();

    // ---- attention scores (72 dots of len 16) ----
    if (t < NHEAD * 9) {
        int h = t / 9, s = t - h * 9;
        const float* qh = qp + h * HDIM;
        const float* kh = &kp[s][h * HDIM];
        float a = 0.f;
        #pragma unroll
        for (int e = 0; e < HDIM; ++e) a = fmaf(qh[e], kh[e], a);
        att[h][s] = a * 0.25f;   // / sqrt(16)
    }
    __syncthreads();

    // ---- softmax over s=9, per head ----
    if (t < NHEAD) {
        float m = att[t][0];
        #pragma unroll
        for (int s = 1; s < 9; ++s) m = fmaxf(m, att[t][s]);
        float e[9]; float sum = 0.f;
        #pragma unroll
        for (int s = 0; s < 9; ++s) { e[s] = expf(att[t][s] - m); sum += e[s]; }
        float inv = 1.0f / sum;
        #pragma unroll
        for (int s = 0; s < 9; ++s) att[t][s] = e[s] * inv;
    }
    __syncthreads();

    // ---- ao = att @ vp ----
    if (t < CH) {
        int h = t >> 4;
        float a = 0.f;
        #pragma unroll
        for (int s = 0; s < 9; ++s) a = fmaf(att[h][s], vp[s][t], a);
        aov[t] = a;
    }
    __syncthreads();

    // ---- ao2 = Wo @ ao + bo; resid; LN1 ----
    float v1 = 0.f;
    if (t < CH) {
        const float4* wr = (const float4*)(Wo + (size_t)t * CH);
        const float4* u4 = (const float4*)aov;
        float s = 0.f;
        #pragma unroll 8
        for (int i = 0; i < CH / 4; ++i) s = dot4(wr[i], u4[i], s);
        v1 = qv[t] + s + bo[t];
    }
    float t1 = block_layernorm(v1, t, g2, be2, redA, redB);
    if (t < CH) tv[t] = t1;
    __syncthreads();

    // ---- FFN: h1 = relu(W1 @ t + b1), 512 outs over 256 threads x2 ----
    #pragma unroll
    for (int rep = 0; rep < 2; ++rep) {
        int o = t + rep * 256;
        const float4* wr = (const float4*)(W1 + (size_t)o * CH);
        const float4* u4 = (const float4*)tv;
        float s = 0.f;
        #pragma unroll 8
        for (int i = 0; i < CH / 4; ++i) s = dot4(wr[i], u4[i], s);
        h1[o] = fmaxf(s + b1[o], 0.f);
    }
    __syncthreads();

    // ---- t2 = W2 @ h1 + b2 : 128 outs, split dot over 2 halves ----
    {
        int o = t & (CH - 1), hf = t >> 7;
        const float4* wr = (const float4*)(W2 + (size_t)o * DFF + hf * (DFF / 2));
        const float4* u4 = (const float4*)(h1 + hf * (DFF / 2));
        float s = 0.f;
        #pragma unroll 8
        for (int i = 0; i < DFF / 8; ++i) s = dot4(wr[i], u4[i], s);
        part[t] = s;
    }
    __syncthreads();

    float v2 = 0.f;
    if (t < CH) {
        float t2 = part[t] + part[t + 128] + b2[t];
        v2 = tv[t] + t2;
    }
    float outv = block_layernorm(v2, t, g3, be3, redA, redB);
    if (t < CH) {
        if (rows) rows[(size_t)det_idx * CH + t] = outv;
        else      out[((size_t)b * CH + t) * HWSZ + p] = outv;
    }
}

__global__ __launch_bounds__(256) void copy_x(const float4* __restrict__ src,
                                              float4* __restrict__ dst, size_t n4) {
    size_t i = (size_t)blockIdx.x * 256 + threadIdx.x;
    const size_t stride = (size_t)gridDim.x * 256;
    for (; i < n4; i += stride) dst[i] = src[i];
}

__global__ __launch_bounds__(256) void scatter_rows(const float* __restrict__ rows,
                                                    const int* __restrict__ inds,
                                                    float* __restrict__ out) {
    int i = blockIdx.x * 256 + threadIdx.x;   // over B*NDET*CH
    int dd = i & (CH - 1);
    int bn = i >> 7;
    int b  = bn >> 7;
    int p  = inds[bn];
    out[((size_t)b * CH + dd) * HWSZ + p] = rows[i];
}

extern "C" void kernel_launch(void* const* d_in, const int* in_sizes, int n_in,
                              void* d_out, int out_size, void* d_ws, size_t ws_size,
                              hipStream_t stream) {
    const float* x    = (const float*)d_in[0];
    const float* vis  = (const float*)d_in[1];
    const int*   dets = (const int*)d_in[2];
    const int*   inds = (const int*)d_in[3];
    const float* Wqkv = (const float*)d_in[4];
    const float* bqkv = (const float*)d_in[5];
    const float* Wo   = (const float*)d_in[6];
    const float* bo   = (const float*)d_in[7];
    const float* W1   = (const float*)d_in[8];
    const float* b1   = (const float*)d_in[9];
    const float* W2   = (const float*)d_in[10];
    const float* b2   = (const float*)d_in[11];
    const float* g2   = (const float*)d_in[12];
    const float* be2  = (const float*)d_in[13];
    const float* g3   = (const float*)d_in[14];
    const float* be3  = (const float*)d_in[15];
    float* out = (float*)d_out;

    const size_t need = (size_t)NDB * CH * sizeof(float);
    if (ws_size >= need) {
        // fused: det blocks interleaved (mod-3) with streaming copy, then scatter
        er_fused<<<dim3(NMIX), dim3(256), 0, stream>>>(
            x, vis, dets, inds, Wqkv, bqkv, Wo, bo, W1, b1, W2, b2,
            g2, be2, g3, be3, out, (float*)d_ws);
        scatter_rows<<<dim3((NDB * CH) / 256), dim3(256), 0, stream>>>(
            (const float*)d_ws, inds, out);
    } else {
        // fallback: copy first, then det blocks write scattered outputs directly
        copy_x<<<dim3(2048), dim3(256), 0, stream>>>(
            (const float4*)x, (float4*)out, (size_t)BB * CH * HWSZ / 4);
        er_fused<<<dim3(NDB), dim3(256), 0, stream>>>(
            x, vis, dets, inds, Wqkv, bqkv, Wo, bo, W1, b1, W2, b2,
            g2, be2, g3, be3, out, nullptr);
    }
}

// Round 4
// 273.095 us; speedup vs baseline: 1.0941x; 1.0941x over previous
//
#include <hip/hip_runtime.h>
#include <math.h>

#define BB 8
#define CH 128
#define HH 152
#define WWID 272
#define HWSZ (HH*WWID)
#define NDET 128
#define NHEAD 8
#define HDIM 16
#define DFF 512
#define NDB (BB*NDET)      // 1024 det blocks (dispatched first -> resident from t=0)
#define NCOPY 2048         // streaming copy blocks

__device__ __forceinline__ float dot4(float4 w, float4 u, float s) {
    s = fmaf(w.x, u.x, s);
    s = fmaf(w.y, u.y, s);
    s = fmaf(w.z, u.z, s);
    s = fmaf(w.w, u.w, s);
    return s;
}

// LayerNorm over 128 values held one-per-thread (t<128); ALL 256 threads must call.
__device__ __forceinline__ float block_layernorm(float v, int t,
        const float* __restrict__ gamma, const float* __restrict__ beta,
        float* redA, float* redB) {
    float s1 = v, s2 = v * v;
    #pragma unroll
    for (int off = 32; off >= 1; off >>= 1) {
        s1 += __shfl_xor(s1, off);
        s2 += __shfl_xor(s2, off);
    }
    if ((t & 63) == 0) { redA[t >> 6] = s1; redB[t >> 6] = s2; }
    __syncthreads();
    float sum = redA[0] + redA[1] + redA[2] + redA[3];
    float sq  = redB[0] + redB[1] + redB[2] + redB[3];
    __syncthreads();
    float m   = sum * (1.0f / 128.0f);
    float var = sq  * (1.0f / 128.0f) - m * m;
    float r = 0.f;
    if (t < CH) r = (v - m) * rsqrtf(var + 1e-5f) * gamma[t] + beta[t];
    return r;
}

__global__ __launch_bounds__(256) void er_fused(
    const float* __restrict__ x, const float* __restrict__ vis,
    const int* __restrict__ dets, const int* __restrict__ inds,
    const float* __restrict__ Wqkv, const float* __restrict__ bqkv,
    const float* __restrict__ Wo,   const float* __restrict__ bo,
    const float* __restrict__ W1,   const float* __restrict__ b1,
    const float* __restrict__ W2,   const float* __restrict__ b2,
    const float* __restrict__ g2,   const float* __restrict__ be2,
    const float* __restrict__ g3,   const float* __restrict__ be3,
    float* __restrict__ out, float* __restrict__ rows)
{
    const int bid = blockIdx.x;
    const int t   = threadIdx.x;

    if (bid >= NDB) {
        // ---- streaming copy x -> out (float4) ----
        const size_t n4 = (size_t)BB * CH * HWSZ / 4;
        const float4* s4 = (const float4*)x;
        float4* o4 = (float4*)out;
        size_t i = (size_t)(bid - NDB) * 256 + t;
        const size_t stride = (size_t)(gridDim.x - NDB) * 256;
        for (; i < n4; i += stride) o4[i] = s4[i];
        return;
    }

    __shared__ float kbuf[9][CH];
    __shared__ float qv[CH];
    __shared__ float qp[CH];
    __shared__ float kp[9][CH];
    __shared__ float vp[9][CH];
    __shared__ float att[NHEAD][9];
    __shared__ float aov[CH];
    __shared__ float tv[CH];
    __shared__ float h1[DFF];
    __shared__ float part[256];
    __shared__ float redA[4], redB[4];
    __shared__ float msk[48][4];   // per-row y-cell masks {m0,m1,m2,0}

    const int det_idx = bid;
    const int b = det_idx >> 7;
    const int n = det_idx & (NDET - 1);

    const int4 dv = *((const int4*)(dets + (size_t)(b * NDET + n) * 4));
    const int sx = dv.x, sy = dv.y, ex = dv.z, ey = dv.w;
    const int Lx = ex - sx, Ly = ey - sy;
    // cell edges (note: cells OVERLAP due to floor/ceil in reference)
    const int xs1 = sx + Lx / 3,        xs2 = sx + 2 * Lx / 3;
    const int xe0 = sx + (Lx + 2) / 3,  xe1 = sx + (2 * Lx + 2) / 3;
    const int ys1 = sy + Ly / 3,        ys2 = sy + 2 * Ly / 3;
    const int ye0 = sy + (Ly + 2) / 3,  ye1 = sy + (2 * Ly + 2) / 3;

    const int p = inds[b * NDET + n];

    // ---- per-row y-masks into LDS (t<48); q gather + vis pos-emb (t<128) ----
    if (t < 48) {
        int y = sy + t;
        bool inb = (y < ey);                     // y >= sy always
        msk[t][0] = (inb && y < ye0)              ? 1.f : 0.f;
        msk[t][1] = (inb && y >= ys1 && y < ye1)  ? 1.f : 0.f;
        msk[t][2] = (inb && y >= ys2)             ? 1.f : 0.f;
        msk[t][3] = 0.f;
    }
    if (t < CH) {
        float qval = x[((size_t)b * CH + t) * HWSZ + p];
        float vv   = vis[(size_t)b * HWSZ + p];
        int vidx   = (int)(vv * 10.0f);
        float fr   = powf(10000.0f, -(float)(t & 126) * (1.0f / 128.0f));
        float ang  = 0.1f * (float)vidx * fr;
        float pe   = (t & 1) ? cosf(ang) : sinf(ang);
        qv[t] = qval + pe;
    }
    __syncthreads();

    // ---- adaptive 3x3 pooling ----
    // 16 groups of 16 lanes; group g handles channels g, g+16, ..., g+112.
    // One float4 per (channel,row) per lane, UNCONDITIONAL (masks zero
    // out-of-box elements; addresses clamped to stay inside the buffer).
    // 8-deep load pipeline: all 8 rows of a chunk in flight before use.
    {
        const int g   = t >> 4;
        const int lx  = t & 15;
        const int sx4 = sx & ~3;               // 16B-aligned start
        const int xb  = sx4 + lx * 4;          // lane's base x (mask domain)
        const int xba = (xb > WWID - 4) ? (WWID - 4) : xb;   // clamped addr

        float4 mx0, mx1, mx2;
        {
            float m0[4], m1[4], m2[4];
            #pragma unroll
            for (int e = 0; e < 4; ++e) {
                int xx = xb + e;
                m0[e] = (xx >= sx  && xx < xe0) ? 1.f : 0.f;
                m1[e] = (xx >= xs1 && xx < xe1) ? 1.f : 0.f;
                m2[e] = (xx >= xs2 && xx < ex ) ? 1.f : 0.f;
            }
            mx0 = make_float4(m0[0], m0[1], m0[2], m0[3]);
            mx1 = make_float4(m1[0], m1[1], m1[2], m1[3]);
            mx2 = make_float4(m2[0], m2[1], m2[2], m2[3]);
        }

        const int rows_n = ey - sy;            // 3..40
        const int nch    = (rows_n + 7) >> 3;  // 1..5 chunks of 8 rows

        for (int c = 0; c < 8; ++c) {
            const int dd = g + c * 16;
            const float* base = x + ((size_t)b * CH + dd) * HWSZ + xba;
            float a[9] = {0.f,0.f,0.f,0.f,0.f,0.f,0.f,0.f,0.f};
            for (int ck = 0; ck < nch; ++ck) {
                const int y0 = sy + (ck << 3);
                float4 v[8];
                #pragma unroll
                for (int k = 0; k < 8; ++k) {
                    int y = y0 + k;
                    y = (y < HH) ? y : (HH - 1);           // clamp; mask is 0 there
                    v[k] = *(const float4*)(base + (size_t)y * WWID);
                }
                #pragma unroll
                for (int k = 0; k < 8; ++k) {
                    const float4 m = *(const float4*)&msk[(y0 - sy) + k][0];
                    float xc0 = dot4(mx0, v[k], 0.f);
                    float xc1 = dot4(mx1, v[k], 0.f);
                    float xc2 = dot4(mx2, v[k], 0.f);
                    a[0] = fmaf(m.x, xc0, a[0]); a[1] = fmaf(m.x, xc1, a[1]); a[2] = fmaf(m.x, xc2, a[2]);
                    a[3] = fmaf(m.y, xc0, a[3]); a[4] = fmaf(m.y, xc1, a[4]); a[5] = fmaf(m.y, xc2, a[5]);
                    a[6] = fmaf(m.z, xc0, a[6]); a[7] = fmaf(m.z, xc1, a[7]); a[8] = fmaf(m.z, xc2, a[8]);
                }
            }
            #pragma unroll
            for (int jj = 0; jj < 9; ++jj) {
                a[jj] += __shfl_xor(a[jj], 8);
                a[jj] += __shfl_xor(a[jj], 4);
                a[jj] += __shfl_xor(a[jj], 2);
                a[jj] += __shfl_xor(a[jj], 1);
            }
            if (lx == 0) {
                int w0 = xe0 - sx, w1 = xe1 - xs1, w2 = ex - xs2;
                int h0 = ye0 - sy, h1r = ye1 - ys1, h2 = ey - ys2;
                kbuf[0][dd] = a[0] / (float)(h0 * w0);
                kbuf[1][dd] = a[1] / (float)(h0 * w1);
                kbuf[2][dd] = a[2] / (float)(h0 * w2);
                kbuf[3][dd] = a[3] / (float)(h1r * w0);
                kbuf[4][dd] = a[4] / (float)(h1r * w1);
                kbuf[5][dd] = a[5] / (float)(h1r * w2);
                kbuf[6][dd] = a[6] / (float)(h2 * w0);
                kbuf[7][dd] = a[7] / (float)(h2 * w1);
                kbuf[8][dd] = a[8] / (float)(h2 * w2);
            }
        }
    }
    __syncthreads();

    // ---- qp = Wq @ q + bq ----
    if (t < CH) {
        const float4* wr = (const float4*)(Wqkv + (size_t)t * CH);
        const float4* qq = (const float4*)qv;
        float s = 0.f;
        #pragma unroll 8
        for (int i = 0; i < CH / 4; ++i) s = dot4(wr[i], qq[i], s);
        qp[t] = s + bqkv[t];
    }

    // ---- kp/vp = {Wk,Wv} @ k + {bk,bv} : 256 threads = 128 outs x {k,v} ----
    {
        const int o = t & (CH - 1);
        const int which = t >> 7;  // 0 -> k, 1 -> v
        const float4* wr = (const float4*)(Wqkv + (size_t)(CH + which * CH + o) * CH);
        float acc[9] = {0.f,0.f,0.f,0.f,0.f,0.f,0.f,0.f,0.f};
        #pragma unroll 4
        for (int i = 0; i < CH / 4; ++i) {
            float4 w = wr[i];
            #pragma unroll
            for (int s = 0; s < 9; ++s) {
                float4 kk = ((const float4*)(&kbuf[s][0]))[i];
                acc[s] = dot4(w, kk, acc[s]);
            }
        }
        float bias = bqkv[CH + which * CH + o];
        if (which == 0) {
            #pragma unroll
            for (int s = 0; s < 9; ++s) kp[s][o] = acc[s] + bias;
        } else {
            #pragma unroll
            for (int s = 0; s < 9; ++s) vp[s][o] = acc[s] + bias;
        }
    }
    __syncthreads();

    // ---- attention scores (72 dots of len 16) ----
    if (t < NHEAD * 9) {
        int h = t / 9, s = t - h * 9;
        const float* qh = qp + h * HDIM;
        const float* kh = &kp[s][h * HDIM];
        float a = 0.f;
        #pragma unroll
        for (int e = 0; e < HDIM; ++e) a = fmaf(qh[e], kh[e], a);
        att[h][s] = a * 0.25f;   // / sqrt(16)
    }
    __syncthreads();

    // ---- softmax over s=9, per head ----
    if (t < NHEAD) {
        float m = att[t][0];
        #pragma unroll
        for (int s = 1; s < 9; ++s) m = fmaxf(m, att[t][s]);
        float e[9]; float sum = 0.f;
        #pragma unroll
        for (int s = 0; s < 9; ++s) { e[s] = expf(att[t][s] - m); sum += e[s]; }
        float inv = 1.0f / sum;
        #pragma unroll
        for (int s = 0; s < 9; ++s) att[t][s] = e[s] * inv;
    }
    __syncthreads();

    // ---- ao = att @ vp ----
    if (t < CH) {
        int h = t >> 4;
        float a = 0.f;
        #pragma unroll
        for (int s = 0; s < 9; ++s) a = fmaf(att[h][s], vp[s][t], a);
        aov[t] = a;
    }
    __syncthreads();

    // ---- ao2 = Wo @ ao + bo; resid; LN1 ----
    float v1 = 0.f;
    if (t < CH) {
        const float4* wr = (const float4*)(Wo + (size_t)t * CH);
        const float4* u4 = (const float4*)aov;
        float s = 0.f;
        #pragma unroll 8
        for (int i = 0; i < CH / 4; ++i) s = dot4(wr[i], u4[i], s);
        v1 = qv[t] + s + bo[t];
    }
    float t1 = block_layernorm(v1, t, g2, be2, redA, redB);
    if (t < CH) tv[t] = t1;
    __syncthreads();

    // ---- FFN: h1 = relu(W1 @ t + b1), 512 outs over 256 threads x2 ----
    #pragma unroll
    for (int rep = 0; rep < 2; ++rep) {
        int o = t + rep * 256;
        const float4* wr = (const float4*)(W1 + (size_t)o * CH);
        const float4* u4 = (const float4*)tv;
        float s = 0.f;
        #pragma unroll 8
        for (int i = 0; i < CH / 4; ++i) s = dot4(wr[i], u4[i], s);
        h1[o] = fmaxf(s + b1[o], 0.f);
    }
    __syncthreads();

    // ---- t2 = W2 @ h1 + b2 : 128 outs, split dot over 2 halves ----
    {
        int o = t & (CH - 1), hf = t >> 7;
        const float4* wr = (const float4*)(W2 + (size_t)o * DFF + hf * (DFF / 2));
        const float4* u4 = (const float4*)(h1 + hf * (DFF / 2));
        float s = 0.f;
        #pragma unroll 8
        for (int i = 0; i < DFF / 8; ++i) s = dot4(wr[i], u4[i], s);
        part[t] = s;
    }
    __syncthreads();

    float v2 = 0.f;
    if (t < CH) {
        float t2 = part[t] + part[t + 128] + b2[t];
        v2 = tv[t] + t2;
    }
    float outv = block_layernorm(v2, t, g3, be3, redA, redB);
    if (t < CH) {
        if (rows) rows[(size_t)det_idx * CH + t] = outv;
        else      out[((size_t)b * CH + t) * HWSZ + p] = outv;
    }
}

__global__ __launch_bounds__(256) void copy_x(const float4* __restrict__ src,
                                              float4* __restrict__ dst, size_t n4) {
    size_t i = (size_t)blockIdx.x * 256 + threadIdx.x;
    const size_t stride = (size_t)gridDim.x * 256;
    for (; i < n4; i += stride) dst[i] = src[i];
}

__global__ __launch_bounds__(256) void scatter_rows(const float* __restrict__ rows,
                                                    const int* __restrict__ inds,
                                                    float* __restrict__ out) {
    int i = blockIdx.x * 256 + threadIdx.x;   // over B*NDET*CH
    int dd = i & (CH - 1);
    int bn = i >> 7;
    int b  = bn >> 7;
    int p  = inds[bn];
    out[((size_t)b * CH + dd) * HWSZ + p] = rows[i];
}

extern "C" void kernel_launch(void* const* d_in, const int* in_sizes, int n_in,
                              void* d_out, int out_size, void* d_ws, size_t ws_size,
                              hipStream_t stream) {
    const float* x    = (const float*)d_in[0];
    const float* vis  = (const float*)d_in[1];
    const int*   dets = (const int*)d_in[2];
    const int*   inds = (const int*)d_in[3];
    const float* Wqkv = (const float*)d_in[4];
    const float* bqkv = (const float*)d_in[5];
    const float* Wo   = (const float*)d_in[6];
    const float* bo   = (const float*)d_in[7];
    const float* W1   = (const float*)d_in[8];
    const float* b1   = (const float*)d_in[9];
    const float* W2   = (const float*)d_in[10];
    const float* b2   = (const float*)d_in[11];
    const float* g2   = (const float*)d_in[12];
    const float* be2  = (const float*)d_in[13];
    const float* g3   = (const float*)d_in[14];
    const float* be3  = (const float*)d_in[15];
    float* out = (float*)d_out;

    const size_t need = (size_t)NDB * CH * sizeof(float);
    if (ws_size >= need) {
        // fused: det blocks first (resident from t=0), copy blocks co-resident
        er_fused<<<dim3(NDB + NCOPY), dim3(256), 0, stream>>>(
            x, vis, dets, inds, Wqkv, bqkv, Wo, bo, W1, b1, W2, b2,
            g2, be2, g3, be3, out, (float*)d_ws);
        scatter_rows<<<dim3((NDB * CH) / 256), dim3(256), 0, stream>>>(
            (const float*)d_ws, inds, out);
    } else {
        // fallback: copy first, then det blocks write scattered outputs directly
        copy_x<<<dim3(NCOPY), dim3(256), 0, stream>>>(
            (const float4*)x, (float4*)out, (size_t)BB * CH * HWSZ / 4);
        er_fused<<<dim3(NDB), dim3(256), 0, stream>>>(
            x, vis, dets, inds, Wqkv, bqkv, Wo, bo, W1, b1, W2, b2,
            g2, be2, g3, be3, out, nullptr);
    }
}

// Round 5
// 199.600 us; speedup vs baseline: 1.4969x; 1.3682x over previous
//
#include <hip/hip_runtime.h>
#include <math.h>

#define BB 8
#define CH 128
#define HH 152
#define WWID 272
#define HWSZ (HH*WWID)
#define NDET 128
#define NHEAD 8
#define HDIM 16
#define DFF 512
#define NDB (BB*NDET)      // 1024 det blocks (dispatched first -> resident from t=0)
#define NCOPY 2048         // streaming copy blocks

typedef float f4v __attribute__((ext_vector_type(4)));

__device__ __forceinline__ float dot4(float4 w, float4 u, float s) {
    s = fmaf(w.x, u.x, s);
    s = fmaf(w.y, u.y, s);
    s = fmaf(w.z, u.z, s);
    s = fmaf(w.w, u.w, s);
    return s;
}

// LayerNorm over 128 values held one-per-thread (t<128); ALL 256 threads must call.
__device__ __forceinline__ float block_layernorm(float v, int t,
        const float* __restrict__ gamma, const float* __restrict__ beta,
        float* redA, float* redB) {
    float s1 = v, s2 = v * v;
    #pragma unroll
    for (int off = 32; off >= 1; off >>= 1) {
        s1 += __shfl_xor(s1, off);
        s2 += __shfl_xor(s2, off);
    }
    if ((t & 63) == 0) { redA[t >> 6] = s1; redB[t >> 6] = s2; }
    __syncthreads();
    float sum = redA[0] + redA[1] + redA[2] + redA[3];
    float sq  = redB[0] + redB[1] + redB[2] + redB[3];
    __syncthreads();
    float m   = sum * (1.0f / 128.0f);
    float var = sq  * (1.0f / 128.0f) - m * m;
    float r = 0.f;
    if (t < CH) r = (v - m) * rsqrtf(var + 1e-5f) * gamma[t] + beta[t];
    return r;
}

__global__ __launch_bounds__(256) void er_fused(
    const float* __restrict__ x, const float* __restrict__ vis,
    const int* __restrict__ dets, const int* __restrict__ inds,
    const float* __restrict__ Wqkv, const float* __restrict__ bqkv,
    const float* __restrict__ Wo,   const float* __restrict__ bo,
    const float* __restrict__ W1,   const float* __restrict__ b1,
    const float* __restrict__ W2,   const float* __restrict__ b2,
    const float* __restrict__ g2,   const float* __restrict__ be2,
    const float* __restrict__ g3,   const float* __restrict__ be3,
    float* __restrict__ out, float* __restrict__ rows)
{
    const int bid = blockIdx.x;
    const int t   = threadIdx.x;

    if (bid >= NDB) {
        // ---- streaming copy x -> out (float4, NON-TEMPORAL stores) ----
        // NT stores keep the 169 MB write from evicting x out of L3, so the
        // det blocks' pooling reads of x stay cache-resident.
        const size_t n4 = (size_t)BB * CH * HWSZ / 4;
        const f4v* s4 = (const f4v*)x;
        f4v* o4 = (f4v*)out;
        size_t i = (size_t)(bid - NDB) * 256 + t;
        const size_t stride = (size_t)(gridDim.x - NDB) * 256;
        for (; i < n4; i += stride) {
            f4v v = s4[i];
            __builtin_nontemporal_store(v, &o4[i]);
        }
        return;
    }

    __shared__ float kbuf[9][CH];
    __shared__ float qv[CH];
    __shared__ float qp[CH];
    __shared__ float kp[9][CH];
    __shared__ float vp[9][CH];
    __shared__ float att[NHEAD][9];
    __shared__ float aov[CH];
    __shared__ float tv[CH];
    __shared__ float h1[DFF];
    __shared__ float part[256];
    __shared__ float redA[4], redB[4];
    __shared__ float msk[48][4];   // per-row y-cell masks {m0,m1,m2,0}

    const int det_idx = bid;
    const int b = det_idx >> 7;
    const int n = det_idx & (NDET - 1);

    const int4 dv = *((const int4*)(dets + (size_t)(b * NDET + n) * 4));
    const int sx = dv.x, sy = dv.y, ex = dv.z, ey = dv.w;
    const int Lx = ex - sx, Ly = ey - sy;
    // cell edges (note: cells OVERLAP due to floor/ceil in reference)
    const int xs1 = sx + Lx / 3,        xs2 = sx + 2 * Lx / 3;
    const int xe0 = sx + (Lx + 2) / 3,  xe1 = sx + (2 * Lx + 2) / 3;
    const int ys1 = sy + Ly / 3,        ys2 = sy + 2 * Ly / 3;
    const int ye0 = sy + (Ly + 2) / 3,  ye1 = sy + (2 * Ly + 2) / 3;

    const int p = inds[b * NDET + n];

    // ---- per-row y-masks into LDS (t<48); q gather + vis pos-emb (t<128) ----
    if (t < 48) {
        int y = sy + t;
        bool inb = (y < ey);                     // y >= sy always
        msk[t][0] = (inb && y < ye0)              ? 1.f : 0.f;
        msk[t][1] = (inb && y >= ys1 && y < ye1)  ? 1.f : 0.f;
        msk[t][2] = (inb && y >= ys2)             ? 1.f : 0.f;
        msk[t][3] = 0.f;
    }
    if (t < CH) {
        float qval = x[((size_t)b * CH + t) * HWSZ + p];
        float vv   = vis[(size_t)b * HWSZ + p];
        int vidx   = (int)(vv * 10.0f);
        float fr   = powf(10000.0f, -(float)(t & 126) * (1.0f / 128.0f));
        float ang  = 0.1f * (float)vidx * fr;
        float pe   = (t & 1) ? cosf(ang) : sinf(ang);
        qv[t] = qval + pe;
    }
    __syncthreads();

    // ---- adaptive 3x3 pooling ----
    // 16 groups of 16 lanes; group g handles channels g, g+16, ..., g+112.
    // Loads are UNCONDITIONAL (deep pipeline) but every address stays INSIDE
    // the box: inactive lanes duplicate the last active lane's base (cache
    // hit, no extra HBM lines); y clamps to ey-1 (in-box row). Masks computed
    // from UNCLAMPED coords zero all duplicated contributions.
    {
        const int g   = t >> 4;
        const int lx  = t & 15;
        const int sx4 = sx & ~3;               // 16B-aligned start
        const int xb  = sx4 + lx * 4;          // lane's base x (mask domain)
        const int lxmax = ((ex - 1) - sx4) >> 2;            // last active lane
        const int xba = sx4 + ((lx < lxmax) ? lx : lxmax) * 4;  // in-box base

        float4 mx0, mx1, mx2;
        {
            float m0[4], m1[4], m2[4];
            #pragma unroll
            for (int e = 0; e < 4; ++e) {
                int xx = xb + e;
                m0[e] = (xx >= sx  && xx < xe0) ? 1.f : 0.f;
                m1[e] = (xx >= xs1 && xx < xe1) ? 1.f : 0.f;
                m2[e] = (xx >= xs2 && xx < ex ) ? 1.f : 0.f;
            }
            mx0 = make_float4(m0[0], m0[1], m0[2], m0[3]);
            mx1 = make_float4(m1[0], m1[1], m1[2], m1[3]);
            mx2 = make_float4(m2[0], m2[1], m2[2], m2[3]);
        }

        const int rows_n = ey - sy;            // 3..40
        const int nch    = (rows_n + 7) >> 3;  // 1..5 chunks of 8 rows

        for (int c = 0; c < 8; ++c) {
            const int dd = g + c * 16;
            const float* base = x + ((size_t)b * CH + dd) * HWSZ + xba;
            float a[9] = {0.f,0.f,0.f,0.f,0.f,0.f,0.f,0.f,0.f};
            for (int ck = 0; ck < nch; ++ck) {
                const int y0 = sy + (ck << 3);
                float4 v[8];
                #pragma unroll
                for (int k = 0; k < 8; ++k) {
                    int y = y0 + k;
                    y = (y < ey) ? y : (ey - 1);           // in-box clamp; mask 0
                    v[k] = *(const float4*)(base + (size_t)y * WWID);
                }
                #pragma unroll
                for (int k = 0; k < 8; ++k) {
                    const float4 m = *(const float4*)&msk[(y0 - sy) + k][0];
                    float xc0 = dot4(mx0, v[k], 0.f);
                    float xc1 = dot4(mx1, v[k], 0.f);
                    float xc2 = dot4(mx2, v[k], 0.f);
                    a[0] = fmaf(m.x, xc0, a[0]); a[1] = fmaf(m.x, xc1, a[1]); a[2] = fmaf(m.x, xc2, a[2]);
                    a[3] = fmaf(m.y, xc0, a[3]); a[4] = fmaf(m.y, xc1, a[4]); a[5] = fmaf(m.y, xc2, a[5]);
                    a[6] = fmaf(m.z, xc0, a[6]); a[7] = fmaf(m.z, xc1, a[7]); a[8] = fmaf(m.z, xc2, a[8]);
                }
            }
            #pragma unroll
            for (int jj = 0; jj < 9; ++jj) {
                a[jj] += __shfl_xor(a[jj], 8);
                a[jj] += __shfl_xor(a[jj], 4);
                a[jj] += __shfl_xor(a[jj], 2);
                a[jj] += __shfl_xor(a[jj], 1);
            }
            if (lx == 0) {
                int w0 = xe0 - sx, w1 = xe1 - xs1, w2 = ex - xs2;
                int h0 = ye0 - sy, h1r = ye1 - ys1, h2 = ey - ys2;
                kbuf[0][dd] = a[0] / (float)(h0 * w0);
                kbuf[1][dd] = a[1] / (float)(h0 * w1);
                kbuf[2][dd] = a[2] / (float)(h0 * w2);
                kbuf[3][dd] = a[3] / (float)(h1r * w0);
                kbuf[4][dd] = a[4] / (float)(h1r * w1);
                kbuf[5][dd] = a[5] / (float)(h1r * w2);
                kbuf[6][dd] = a[6] / (float)(h2 * w0);
                kbuf[7][dd] = a[7] / (float)(h2 * w1);
                kbuf[8][dd] = a[8] / (float)(h2 * w2);
            }
        }
    }
    __syncthreads();

    // ---- qp = Wq @ q + bq ----
    if (t < CH) {
        const float4* wr = (const float4*)(Wqkv + (size_t)t * CH);
        const float4* qq = (const float4*)qv;
        float s = 0.f;
        #pragma unroll 8
        for (int i = 0; i < CH / 4; ++i) s = dot4(wr[i], qq[i], s);
        qp[t] = s + bqkv[t];
    }

    // ---- kp/vp = {Wk,Wv} @ k + {bk,bv} : 256 threads = 128 outs x {k,v} ----
    {
        const int o = t & (CH - 1);
        const int which = t >> 7;  // 0 -> k, 1 -> v
        const float4* wr = (const float4*)(Wqkv + (size_t)(CH + which * CH + o) * CH);
        float acc[9] = {0.f,0.f,0.f,0.f,0.f,0.f,0.f,0.f,0.f};
        #pragma unroll 4
        for (int i = 0; i < CH / 4; ++i) {
            float4 w = wr[i];
            #pragma unroll
            for (int s = 0; s < 9; ++s) {
                float4 kk = ((const float4*)(&kbuf[s][0]))[i];
                acc[s] = dot4(w, kk, acc[s]);
            }
        }
        float bias = bqkv[CH + which * CH + o];
        if (which == 0) {
            #pragma unroll
            for (int s = 0; s < 9; ++s) kp[s][o] = acc[s] + bias;
        } else {
            #pragma unroll
            for (int s = 0; s < 9; ++s) vp[s][o] = acc[s] + bias;
        }
    }
    __syncthreads();

    // ---- attention scores (72 dots of len 16) ----
    if (t < NHEAD * 9) {
        int h = t / 9, s = t - h * 9;
        const float* qh = qp + h * HDIM;
        const float* kh = &kp[s][h * HDIM];
        float a = 0.f;
        #pragma unroll
        for (int e = 0; e < HDIM; ++e) a = fmaf(qh[e], kh[e], a);
        att[h][s] = a * 0.25f;   // / sqrt(16)
    }
    __syncthreads();

    // ---- softmax over s=9, per head ----
    if (t < NHEAD) {
        float m = att[t][0];
        #pragma unroll
        for (int s = 1; s < 9; ++s) m = fmaxf(m, att[t][s]);
        float e[9]; float sum = 0.f;
        #pragma unroll
        for (int s = 0; s < 9; ++s) { e[s] = expf(att[t][s] - m); sum += e[s]; }
        float inv = 1.0f / sum;
        #pragma unroll
        for (int s = 0; s < 9; ++s) att[t][s] = e[s] * inv;
    }
    __syncthreads();

    // ---- ao = att @ vp ----
    if (t < CH) {
        int h = t >> 4;
        float a = 0.f;
        #pragma unroll
        for (int s = 0; s < 9; ++s) a = fmaf(att[h][s], vp[s][t], a);
        aov[t] = a;
    }
    __syncthreads();

    // ---- ao2 = Wo @ ao + bo; resid; LN1 ----
    float v1 = 0.f;
    if (t < CH) {
        const float4* wr = (const float4*)(Wo + (size_t)t * CH);
        const float4* u4 = (const float4*)aov;
        float s = 0.f;
        #pragma unroll 8
        for (int i = 0; i < CH / 4; ++i) s = dot4(wr[i], u4[i], s);
        v1 = qv[t] + s + bo[t];
    }
    float t1 = block_layernorm(v1, t, g2, be2, redA, redB);
    if (t < CH) tv[t] = t1;
    __syncthreads();

    // ---- FFN: h1 = relu(W1 @ t + b1), 512 outs over 256 threads x2 ----
    #pragma unroll
    for (int rep = 0; rep < 2; ++rep) {
        int o = t + rep * 256;
        const float4* wr = (const float4*)(W1 + (size_t)o * CH);
        const float4* u4 = (const float4*)tv;
        float s = 0.f;
        #pragma unroll 8
        for (int i = 0; i < CH / 4; ++i) s = dot4(wr[i], u4[i], s);
        h1[o] = fmaxf(s + b1[o], 0.f);
    }
    __syncthreads();

    // ---- t2 = W2 @ h1 + b2 : 128 outs, split dot over 2 halves ----
    {
        int o = t & (CH - 1), hf = t >> 7;
        const float4* wr = (const float4*)(W2 + (size_t)o * DFF + hf * (DFF / 2));
        const float4* u4 = (const float4*)(h1 + hf * (DFF / 2));
        float s = 0.f;
        #pragma unroll 8
        for (int i = 0; i < DFF / 8; ++i) s = dot4(wr[i], u4[i], s);
        part[t] = s;
    }
    __syncthreads();

    float v2 = 0.f;
    if (t < CH) {
        float t2 = part[t] + part[t + 128] + b2[t];
        v2 = tv[t] + t2;
    }
    float outv = block_layernorm(v2, t, g3, be3, redA, redB);
    if (t < CH) {
        if (rows) rows[(size_t)det_idx * CH + t] = outv;
        else      out[((size_t)b * CH + t) * HWSZ + p] = outv;
    }
}

__global__ __launch_bounds__(256) void copy_x(const f4v* __restrict__ src,
                                              f4v* __restrict__ dst, size_t n4) {
    size_t i = (size_t)blockIdx.x * 256 + threadIdx.x;
    const size_t stride = (size_t)gridDim.x * 256;
    for (; i < n4; i += stride) {
        f4v v = src[i];
        __builtin_nontemporal_store(v, &dst[i]);
    }
}

__global__ __launch_bounds__(256) void scatter_rows(const float* __restrict__ rows,
                                                    const int* __restrict__ inds,
                                                    float* __restrict__ out) {
    int i = blockIdx.x * 256 + threadIdx.x;   // over B*NDET*CH
    int dd = i & (CH - 1);
    int bn = i >> 7;
    int b  = bn >> 7;
    int p  = inds[bn];
    out[((size_t)b * CH + dd) * HWSZ + p] = rows[i];
}

extern "C" void kernel_launch(void* const* d_in, const int* in_sizes, int n_in,
                              void* d_out, int out_size, void* d_ws, size_t ws_size,
                              hipStream_t stream) {
    const float* x    = (const float*)d_in[0];
    const float* vis  = (const float*)d_in[1];
    const int*   dets = (const int*)d_in[2];
    const int*   inds = (const int*)d_in[3];
    const float* Wqkv = (const float*)d_in[4];
    const float* bqkv = (const float*)d_in[5];
    const float* Wo   = (const float*)d_in[6];
    const float* bo   = (const float*)d_in[7];
    const float* W1   = (const float*)d_in[8];
    const float* b1   = (const float*)d_in[9];
    const float* W2   = (const float*)d_in[10];
    const float* b2   = (const float*)d_in[11];
    const float* g2   = (const float*)d_in[12];
    const float* be2  = (const float*)d_in[13];
    const float* g3   = (const float*)d_in[14];
    const float* be3  = (const float*)d_in[15];
    float* out = (float*)d_out;

    const size_t need = (size_t)NDB * CH * sizeof(float);
    if (ws_size >= need) {
        // fused: det blocks first (resident from t=0), copy blocks co-resident
        er_fused<<<dim3(NDB + NCOPY), dim3(256), 0, stream>>>(
            x, vis, dets, inds, Wqkv, bqkv, Wo, bo, W1, b1, W2, b2,
            g2, be2, g3, be3, out, (float*)d_ws);
        scatter_rows<<<dim3((NDB * CH) / 256), dim3(256), 0, stream>>>(
            (const float*)d_ws, inds, out);
    } else {
        // fallback: copy first, then det blocks write scattered outputs directly
        copy_x<<<dim3(NCOPY), dim3(256), 0, stream>>>(
            (const f4v*)x, (f4v*)out, (size_t)BB * CH * HWSZ / 4);
        er_fused<<<dim3(NDB), dim3(256), 0, stream>>>(
            x, vis, dets, inds, Wqkv, bqkv, Wo, bo, W1, b1, W2, b2,
            g2, be2, g3, be3, out, nullptr);
    }
}